// Round 2
// baseline (219.011 us; speedup 1.0000x reference)
//
#include <hip/hip_runtime.h>

#define SEQ 8
#define DIM 16
#define FF 32
#define VOCAB 256
#define ITEMS_PER_BLOCK 32
#define ITEM_STRIDE 136  // 8 rows * 16 dwords + 8 pad dwords (breaks bank aliasing)

__global__ __launch_bounds__(256) void transformer_fused_kernel(
    const int* __restrict__ x,
    const float* __restrict__ token_embed,
    const float* __restrict__ pos_embed,
    const float* __restrict__ Wq, const float* __restrict__ bq,
    const float* __restrict__ Wk, const float* __restrict__ bk,
    const float* __restrict__ Wv, const float* __restrict__ bv,
    const float* __restrict__ Wo, const float* __restrict__ bo,
    const float* __restrict__ W1, const float* __restrict__ b1,
    const float* __restrict__ W2, const float* __restrict__ b2,
    const float* __restrict__ Wh, const float* __restrict__ bh,
    float* __restrict__ out)
{
    __shared__ float sK[ITEMS_PER_BLOCK * ITEM_STRIDE];
    __shared__ float sV[ITEMS_PER_BLOCK * ITEM_STRIDE];

    const int tid = threadIdx.x;
    const int i = tid >> 3;   // local batch item 0..31
    const int n = tid & 7;    // seq position 0..7
    const int b = blockIdx.x * ITEMS_PER_BLOCK + i;

    // ---------------- phase 1: embedding + QKV ----------------
    float X[DIM];
    {
        const int idx = x[b * SEQ + n];
        const float4* te = (const float4*)(token_embed + idx * DIM);
        const float4* pe = (const float4*)(pos_embed + n * DIM);
        #pragma unroll
        for (int j = 0; j < 4; ++j) {
            float4 a = te[j];
            float4 p = pe[j];
            X[4*j+0] = a.x + p.x;
            X[4*j+1] = a.y + p.y;
            X[4*j+2] = a.z + p.z;
            X[4*j+3] = a.w + p.w;
        }
    }

    float Q[DIM], Kr[DIM], Vr[DIM];
    #pragma unroll
    for (int e = 0; e < DIM; ++e) {
        float q = bq[e], k = bk[e], v = bv[e];
        #pragma unroll
        for (int d = 0; d < DIM; ++d) {
            q += X[d] * Wq[d * DIM + e];
            k += X[d] * Wk[d * DIM + e];
            v += X[d] * Wv[d * DIM + e];
        }
        Q[e] = q; Kr[e] = k; Vr[e] = v;
    }

    // park K,V rows in LDS
    {
        float* kdst = sK + i * ITEM_STRIDE + n * DIM;
        float* vdst = sV + i * ITEM_STRIDE + n * DIM;
        #pragma unroll
        for (int j = 0; j < 4; ++j) {
            float4 kk, vv;
            kk.x = Kr[4*j+0]; kk.y = Kr[4*j+1]; kk.z = Kr[4*j+2]; kk.w = Kr[4*j+3];
            vv.x = Vr[4*j+0]; vv.y = Vr[4*j+1]; vv.z = Vr[4*j+2]; vv.w = Vr[4*j+3];
            ((float4*)kdst)[j] = kk;
            ((float4*)vdst)[j] = vv;
        }
    }
    __syncthreads();

    // ---------------- attention (seq=8, per-thread softmax) ----------------
    float sc[SEQ];
    #pragma unroll
    for (int m = 0; m < SEQ; ++m) {
        const float* kr = sK + i * ITEM_STRIDE + m * DIM;
        float s = 0.f;
        #pragma unroll
        for (int d = 0; d < DIM; ++d) s += Q[d] * kr[d];
        sc[m] = s * 0.25f;  // 1/sqrt(16)
    }
    float mx = sc[0];
    #pragma unroll
    for (int m = 1; m < SEQ; ++m) mx = fmaxf(mx, sc[m]);
    float sum = 0.f;
    #pragma unroll
    for (int m = 0; m < SEQ; ++m) { sc[m] = __expf(sc[m] - mx); sum += sc[m]; }
    const float inv = 1.0f / sum;

    float at[DIM];
    #pragma unroll
    for (int d = 0; d < DIM; ++d) at[d] = 0.f;
    #pragma unroll
    for (int m = 0; m < SEQ; ++m) {
        const float w = sc[m] * inv;
        const float* vr = sV + i * ITEM_STRIDE + m * DIM;
        #pragma unroll
        for (int d = 0; d < DIM; ++d) at[d] += w * vr[d];
    }

    // ---------------- O projection + residual ----------------
    float X1[DIM];
    #pragma unroll
    for (int e = 0; e < DIM; ++e) {
        float o = bo[e];
        #pragma unroll
        for (int d = 0; d < DIM; ++d) o += at[d] * Wo[d * DIM + e];
        X1[e] = X[e] + o;
    }

    // ---------------- FFN + residual ----------------
    float h[FF];
    #pragma unroll
    for (int f = 0; f < FF; ++f) {
        float a = b1[f];
        #pragma unroll
        for (int d = 0; d < DIM; ++d) a += X1[d] * W1[d * FF + f];
        h[f] = fmaxf(a, 0.f);
    }
    float X2[DIM];
    #pragma unroll
    for (int e = 0; e < DIM; ++e) {
        float a = b2[e];
        #pragma unroll
        for (int f = 0; f < FF; ++f) a += h[f] * W2[f * DIM + e];
        X2[e] = X1[e] + a;
    }

    __syncthreads();  // everyone done reading sK/sV

    // park final X rows in LDS (reuse sK)
    {
        float* xdst = sK + i * ITEM_STRIDE + n * DIM;
        #pragma unroll
        for (int j = 0; j < 4; ++j) {
            float4 xx;
            xx.x = X2[4*j+0]; xx.y = X2[4*j+1]; xx.z = X2[4*j+2]; xx.w = X2[4*j+3];
            ((float4*)xdst)[j] = xx;
        }
    }
    __syncthreads();

    // ---------------- phase 2: vocab head ----------------
    // Wave w owns the 64 rows its own lanes produced (rows 64w..64w+63).
    // Lane l owns vocab columns 4l..4l+3 -> one float4 store per row,
    // 4 uniform ds_read_b128 per row (broadcast), 64 FMA per row.
    const int w = tid >> 6;   // wave id 0..3
    const int l = tid & 63;   // lane id

    float4 wh4[DIM];
    #pragma unroll
    for (int d = 0; d < DIM; ++d)
        wh4[d] = *(const float4*)(Wh + d * VOCAB + 4 * l);
    const float4 bh4 = *(const float4*)(bh + 4 * l);

    const size_t row0 = (size_t)blockIdx.x * (ITEMS_PER_BLOCK * SEQ) + 64 * w;
    #pragma unroll 4
    for (int r = 0; r < 64; ++r) {
        const float* xr = sK + (8 * w + (r >> 3)) * ITEM_STRIDE + (r & 7) * DIM;
        float4 acc = bh4;
        #pragma unroll
        for (int d = 0; d < DIM; ++d) {
            const float xv = xr[d];
            acc.x += xv * wh4[d].x;
            acc.y += xv * wh4[d].y;
            acc.z += xv * wh4[d].z;
            acc.w += xv * wh4[d].w;
        }
        *(float4*)(out + (row0 + r) * VOCAB + 4 * l) = acc;
    }
}

extern "C" void kernel_launch(void* const* d_in, const int* in_sizes, int n_in,
                              void* d_out, int out_size, void* d_ws, size_t ws_size,
                              hipStream_t stream) {
    const int*   x           = (const int*)  d_in[0];
    const float* token_embed = (const float*)d_in[1];
    const float* pos_embed   = (const float*)d_in[2];
    const float* Wq = (const float*)d_in[3];
    const float* bq = (const float*)d_in[4];
    const float* Wk = (const float*)d_in[5];
    const float* bk = (const float*)d_in[6];
    const float* Wv = (const float*)d_in[7];
    const float* bv = (const float*)d_in[8];
    const float* Wo = (const float*)d_in[9];
    const float* bo = (const float*)d_in[10];
    const float* W1 = (const float*)d_in[11];
    const float* b1 = (const float*)d_in[12];
    const float* W2 = (const float*)d_in[13];
    const float* b2 = (const float*)d_in[14];
    const float* Wh = (const float*)d_in[15];
    const float* bh = (const float*)d_in[16];
    float* out = (float*)d_out;

    const int B = in_sizes[0] / SEQ;                 // 32768
    const int grid = B / ITEMS_PER_BLOCK;            // 1024 blocks
    transformer_fused_kernel<<<grid, 256, 0, stream>>>(
        x, token_embed, pos_embed, Wq, bq, Wk, bk, Wv, bv, Wo, bo,
        W1, b1, W2, b2, Wh, bh, out);
}

// Round 3
// 207.908 us; speedup vs baseline: 1.0534x; 1.0534x over previous
//
#include <hip/hip_runtime.h>

#define SEQ 8
#define DIM 16
#define FF 32
#define VOCAB 256
#define ITEMS_PER_BLOCK 32
#define ITEM_STRIDE 136  // 8 rows * 16 dwords + 8 pad dwords

// ---------------------------------------------------------------------------
// Kernel A: per-row transformer body (embed -> QKV -> attn -> FFN -> X2)
// One thread per (b, n) row. Writes X2 [B*SEQ, 16] f32 to workspace.
// ---------------------------------------------------------------------------
__global__ __launch_bounds__(256) void body_kernel(
    const int* __restrict__ x,
    const float* __restrict__ token_embed,
    const float* __restrict__ pos_embed,
    const float* __restrict__ Wq, const float* __restrict__ bq,
    const float* __restrict__ Wk, const float* __restrict__ bk,
    const float* __restrict__ Wv, const float* __restrict__ bv,
    const float* __restrict__ Wo, const float* __restrict__ bo,
    const float* __restrict__ W1, const float* __restrict__ b1,
    const float* __restrict__ W2, const float* __restrict__ b2,
    float* __restrict__ xout)
{
    __shared__ float sK[ITEMS_PER_BLOCK * ITEM_STRIDE];
    __shared__ float sV[ITEMS_PER_BLOCK * ITEM_STRIDE];

    const int tid = threadIdx.x;
    const int i = tid >> 3;   // local batch item 0..31
    const int n = tid & 7;    // seq position 0..7
    const int b = blockIdx.x * ITEMS_PER_BLOCK + i;

    float X[DIM];
    {
        const int idx = x[b * SEQ + n];
        const float4* te = (const float4*)(token_embed + idx * DIM);
        const float4* pe = (const float4*)(pos_embed + n * DIM);
        #pragma unroll
        for (int j = 0; j < 4; ++j) {
            float4 a = te[j];
            float4 p = pe[j];
            X[4*j+0] = a.x + p.x;
            X[4*j+1] = a.y + p.y;
            X[4*j+2] = a.z + p.z;
            X[4*j+3] = a.w + p.w;
        }
    }

    float Q[DIM], Kr[DIM], Vr[DIM];
    #pragma unroll
    for (int e = 0; e < DIM; ++e) {
        float q = bq[e], k = bk[e], v = bv[e];
        #pragma unroll
        for (int d = 0; d < DIM; ++d) {
            q += X[d] * Wq[d * DIM + e];
            k += X[d] * Wk[d * DIM + e];
            v += X[d] * Wv[d * DIM + e];
        }
        Q[e] = q; Kr[e] = k; Vr[e] = v;
    }

    {
        float* kdst = sK + i * ITEM_STRIDE + n * DIM;
        float* vdst = sV + i * ITEM_STRIDE + n * DIM;
        #pragma unroll
        for (int j = 0; j < 4; ++j) {
            float4 kk, vv;
            kk.x = Kr[4*j+0]; kk.y = Kr[4*j+1]; kk.z = Kr[4*j+2]; kk.w = Kr[4*j+3];
            vv.x = Vr[4*j+0]; vv.y = Vr[4*j+1]; vv.z = Vr[4*j+2]; vv.w = Vr[4*j+3];
            ((float4*)kdst)[j] = kk;
            ((float4*)vdst)[j] = vv;
        }
    }
    __syncthreads();

    float sc[SEQ];
    #pragma unroll
    for (int m = 0; m < SEQ; ++m) {
        const float* kr = sK + i * ITEM_STRIDE + m * DIM;
        float s = 0.f;
        #pragma unroll
        for (int d = 0; d < DIM; ++d) s += Q[d] * kr[d];
        sc[m] = s * 0.25f;
    }
    float mx = sc[0];
    #pragma unroll
    for (int m = 1; m < SEQ; ++m) mx = fmaxf(mx, sc[m]);
    float sum = 0.f;
    #pragma unroll
    for (int m = 0; m < SEQ; ++m) { sc[m] = __expf(sc[m] - mx); sum += sc[m]; }
    const float inv = 1.0f / sum;

    float at[DIM];
    #pragma unroll
    for (int d = 0; d < DIM; ++d) at[d] = 0.f;
    #pragma unroll
    for (int m = 0; m < SEQ; ++m) {
        const float w = sc[m] * inv;
        const float* vr = sV + i * ITEM_STRIDE + m * DIM;
        #pragma unroll
        for (int d = 0; d < DIM; ++d) at[d] += w * vr[d];
    }

    float X1[DIM];
    #pragma unroll
    for (int e = 0; e < DIM; ++e) {
        float o = bo[e];
        #pragma unroll
        for (int d = 0; d < DIM; ++d) o += at[d] * Wo[d * DIM + e];
        X1[e] = X[e] + o;
    }

    float h[FF];
    #pragma unroll
    for (int f = 0; f < FF; ++f) {
        float a = b1[f];
        #pragma unroll
        for (int d = 0; d < DIM; ++d) a += X1[d] * W1[d * FF + f];
        h[f] = fmaxf(a, 0.f);
    }
    float X2[DIM];
    #pragma unroll
    for (int e = 0; e < DIM; ++e) {
        float a = b2[e];
        #pragma unroll
        for (int f = 0; f < FF; ++f) a += h[f] * W2[f * DIM + e];
        X2[e] = X1[e] + a;
    }

    // write X2 row to workspace
    const size_t row = (size_t)b * SEQ + n;
    float4* dst = (float4*)(xout + row * DIM);
    #pragma unroll
    for (int j = 0; j < 4; ++j) {
        float4 xx;
        xx.x = X2[4*j+0]; xx.y = X2[4*j+1]; xx.z = X2[4*j+2]; xx.w = X2[4*j+3];
        dst[j] = xx;
    }
}

// ---------------------------------------------------------------------------
// Kernel B: vocab head GEMM [R,16] @ [16,256] + bias.
// Wave w of each block owns column quarter w (cols 64w..64w+63, 1 col/lane,
// 16 weight VGPRs). X row pointer is wave-uniform -> s_load_dwordx16.
// Per row per wave: 1 s_load + 16 v_fmac + 1 coalesced 256B store.
// ---------------------------------------------------------------------------
#define ROWS_PER_BLOCK 32

__global__ __launch_bounds__(256) void head_kernel(
    const float* __restrict__ xin,
    const float* __restrict__ Wh,
    const float* __restrict__ bh,
    float* __restrict__ out)
{
    const int tid = threadIdx.x;
    const int col = tid;              // wave w covers cols 64w..64w+63
    float wh[DIM];
    #pragma unroll
    for (int d = 0; d < DIM; ++d) wh[d] = Wh[d * VOCAB + col];
    const float bhv = bh[col];

    const size_t row0 = (size_t)blockIdx.x * ROWS_PER_BLOCK;
    #pragma unroll 4
    for (int r = 0; r < ROWS_PER_BLOCK; ++r) {
        const float* xr = xin + (row0 + r) * DIM;  // wave-uniform address
        float acc = bhv;
        #pragma unroll
        for (int d = 0; d < DIM; ++d) acc += xr[d] * wh[d];
        out[(row0 + r) * VOCAB + col] = acc;
    }
}

// ---------------------------------------------------------------------------
// Fallback: round-1 fused single kernel (used only if ws too small)
// ---------------------------------------------------------------------------
__global__ __launch_bounds__(256) void fused_fallback_kernel(
    const int* __restrict__ x,
    const float* __restrict__ token_embed,
    const float* __restrict__ pos_embed,
    const float* __restrict__ Wq, const float* __restrict__ bq,
    const float* __restrict__ Wk, const float* __restrict__ bk,
    const float* __restrict__ Wv, const float* __restrict__ bv,
    const float* __restrict__ Wo, const float* __restrict__ bo,
    const float* __restrict__ W1, const float* __restrict__ b1,
    const float* __restrict__ W2, const float* __restrict__ b2,
    const float* __restrict__ Wh, const float* __restrict__ bh,
    float* __restrict__ out)
{
    __shared__ float sK[ITEMS_PER_BLOCK * ITEM_STRIDE];
    __shared__ float sV[ITEMS_PER_BLOCK * ITEM_STRIDE];

    const int tid = threadIdx.x;
    const int i = tid >> 3;
    const int n = tid & 7;
    const int b = blockIdx.x * ITEMS_PER_BLOCK + i;

    float X[DIM];
    {
        const int idx = x[b * SEQ + n];
        const float4* te = (const float4*)(token_embed + idx * DIM);
        const float4* pe = (const float4*)(pos_embed + n * DIM);
        #pragma unroll
        for (int j = 0; j < 4; ++j) {
            float4 a = te[j];
            float4 p = pe[j];
            X[4*j+0] = a.x + p.x; X[4*j+1] = a.y + p.y;
            X[4*j+2] = a.z + p.z; X[4*j+3] = a.w + p.w;
        }
    }

    float Q[DIM], Kr[DIM], Vr[DIM];
    #pragma unroll
    for (int e = 0; e < DIM; ++e) {
        float q = bq[e], k = bk[e], v = bv[e];
        #pragma unroll
        for (int d = 0; d < DIM; ++d) {
            q += X[d] * Wq[d * DIM + e];
            k += X[d] * Wk[d * DIM + e];
            v += X[d] * Wv[d * DIM + e];
        }
        Q[e] = q; Kr[e] = k; Vr[e] = v;
    }
    {
        float* kdst = sK + i * ITEM_STRIDE + n * DIM;
        float* vdst = sV + i * ITEM_STRIDE + n * DIM;
        #pragma unroll
        for (int j = 0; j < 4; ++j) {
            float4 kk, vv;
            kk.x = Kr[4*j+0]; kk.y = Kr[4*j+1]; kk.z = Kr[4*j+2]; kk.w = Kr[4*j+3];
            vv.x = Vr[4*j+0]; vv.y = Vr[4*j+1]; vv.z = Vr[4*j+2]; vv.w = Vr[4*j+3];
            ((float4*)kdst)[j] = kk;
            ((float4*)vdst)[j] = vv;
        }
    }
    __syncthreads();

    float sc[SEQ];
    #pragma unroll
    for (int m = 0; m < SEQ; ++m) {
        const float* kr = sK + i * ITEM_STRIDE + m * DIM;
        float s = 0.f;
        #pragma unroll
        for (int d = 0; d < DIM; ++d) s += Q[d] * kr[d];
        sc[m] = s * 0.25f;
    }
    float mx = sc[0];
    #pragma unroll
    for (int m = 1; m < SEQ; ++m) mx = fmaxf(mx, sc[m]);
    float sum = 0.f;
    #pragma unroll
    for (int m = 0; m < SEQ; ++m) { sc[m] = __expf(sc[m] - mx); sum += sc[m]; }
    const float inv = 1.0f / sum;

    float at[DIM];
    #pragma unroll
    for (int d = 0; d < DIM; ++d) at[d] = 0.f;
    #pragma unroll
    for (int m = 0; m < SEQ; ++m) {
        const float w = sc[m] * inv;
        const float* vr = sV + i * ITEM_STRIDE + m * DIM;
        #pragma unroll
        for (int d = 0; d < DIM; ++d) at[d] += w * vr[d];
    }

    float X1[DIM];
    #pragma unroll
    for (int e = 0; e < DIM; ++e) {
        float o = bo[e];
        #pragma unroll
        for (int d = 0; d < DIM; ++d) o += at[d] * Wo[d * DIM + e];
        X1[e] = X[e] + o;
    }
    float h[FF];
    #pragma unroll
    for (int f = 0; f < FF; ++f) {
        float a = b1[f];
        #pragma unroll
        for (int d = 0; d < DIM; ++d) a += X1[d] * W1[d * FF + f];
        h[f] = fmaxf(a, 0.f);
    }
    float X2[DIM];
    #pragma unroll
    for (int e = 0; e < DIM; ++e) {
        float a = b2[e];
        #pragma unroll
        for (int f = 0; f < FF; ++f) a += h[f] * W2[f * DIM + e];
        X2[e] = X1[e] + a;
    }

    __syncthreads();
    {
        float* xdst = sK + i * ITEM_STRIDE + n * DIM;
        #pragma unroll
        for (int j = 0; j < 4; ++j) {
            float4 xx;
            xx.x = X2[4*j+0]; xx.y = X2[4*j+1]; xx.z = X2[4*j+2]; xx.w = X2[4*j+3];
            ((float4*)xdst)[j] = xx;
        }
    }
    __syncthreads();

    float wh[DIM];
    #pragma unroll
    for (int d = 0; d < DIM; ++d) wh[d] = Wh[d * VOCAB + tid];
    const float bhv = bh[tid];

    const size_t obase = (size_t)blockIdx.x * (ITEMS_PER_BLOCK * SEQ) * VOCAB + tid;
    #pragma unroll 4
    for (int r = 0; r < ITEMS_PER_BLOCK * SEQ; ++r) {
        const float* xr = sK + (r >> 3) * ITEM_STRIDE + (r & 7) * DIM;
        float acc = bhv;
        #pragma unroll
        for (int d = 0; d < DIM; ++d) acc += xr[d] * wh[d];
        out[obase + (size_t)r * VOCAB] = acc;
    }
}

extern "C" void kernel_launch(void* const* d_in, const int* in_sizes, int n_in,
                              void* d_out, int out_size, void* d_ws, size_t ws_size,
                              hipStream_t stream) {
    const int*   x           = (const int*)  d_in[0];
    const float* token_embed = (const float*)d_in[1];
    const float* pos_embed   = (const float*)d_in[2];
    const float* Wq = (const float*)d_in[3];
    const float* bq = (const float*)d_in[4];
    const float* Wk = (const float*)d_in[5];
    const float* bk = (const float*)d_in[6];
    const float* Wv = (const float*)d_in[7];
    const float* bv = (const float*)d_in[8];
    const float* Wo = (const float*)d_in[9];
    const float* bo = (const float*)d_in[10];
    const float* W1 = (const float*)d_in[11];
    const float* b1 = (const float*)d_in[12];
    const float* W2 = (const float*)d_in[13];
    const float* b2 = (const float*)d_in[14];
    const float* Wh = (const float*)d_in[15];
    const float* bh = (const float*)d_in[16];
    float* out = (float*)d_out;

    const int B = in_sizes[0] / SEQ;                 // 32768
    const int nrows = B * SEQ;                       // 262144
    const size_t ws_needed = (size_t)nrows * DIM * sizeof(float);  // 16 MB

    if (ws_size >= ws_needed) {
        float* xws = (float*)d_ws;
        body_kernel<<<B / ITEMS_PER_BLOCK, 256, 0, stream>>>(
            x, token_embed, pos_embed, Wq, bq, Wk, bk, Wv, bv, Wo, bo,
            W1, b1, W2, b2, xws);
        head_kernel<<<nrows / ROWS_PER_BLOCK, 256, 0, stream>>>(
            xws, Wh, bh, out);
    } else {
        fused_fallback_kernel<<<B / ITEMS_PER_BLOCK, 256, 0, stream>>>(
            x, token_embed, pos_embed, Wq, bq, Wk, bk, Wv, bv, Wo, bo,
            W1, b1, W2, b2, Wh, bh, out);
    }
}

// Round 4
// 97.354 us; speedup vs baseline: 2.2496x; 2.1356x over previous
//
#include <hip/hip_runtime.h>

#define SEQ 8
#define DIM 16
#define FF 32
#define VOCAB 256

// float-valued ds_swizzle with XOR pattern: src_lane = lane ^ T (T < 8 stays
// inside the 8-lane item group and inside each 32-lane half).
// BitMode offset = (xor<<10) | (or<<5) | and, and=0x1F.
#define SWZF(val, imm) __int_as_float(__builtin_amdgcn_ds_swizzle(__float_as_int(val), (imm)))

// ---------------------------------------------------------------------------
// Kernel A: per-row transformer body (embed -> QKV -> attn -> FFN -> X2).
// One thread per (b, n) row; the 8 rows of one item sit in 8 consecutive
// lanes of one wave -> K/V exchanged with ds_swizzle XOR, zero LDS, no
// barriers. Weights stream through s_load (wave-uniform addresses) as SGPR
// operands of v_fmac. Outer-product ordering gives 16..48 independent
// accumulator chains.
// ---------------------------------------------------------------------------
__global__ __launch_bounds__(256, 4) void body_kernel(
    const int* __restrict__ x,
    const float* __restrict__ token_embed,
    const float* __restrict__ pos_embed,
    const float* __restrict__ Wq, const float* __restrict__ bq,
    const float* __restrict__ Wk, const float* __restrict__ bk,
    const float* __restrict__ Wv, const float* __restrict__ bv,
    const float* __restrict__ Wo, const float* __restrict__ bo,
    const float* __restrict__ W1, const float* __restrict__ b1,
    const float* __restrict__ W2, const float* __restrict__ b2,
    float* __restrict__ xout)
{
    const int tid = threadIdx.x;
    const int n = tid & 7;                                   // seq position
    const size_t row = (size_t)blockIdx.x * 256 + tid;       // global row id

    // ---------------- embedding + positional ----------------
    float X[DIM];
    {
        const int idx = x[row];
        const float4* te = (const float4*)(token_embed + (size_t)idx * DIM);
        const float4* pe = (const float4*)(pos_embed + n * DIM);
        #pragma unroll
        for (int j = 0; j < 4; ++j) {
            float4 a = te[j];
            float4 p = pe[j];
            X[4*j+0] = a.x + p.x;
            X[4*j+1] = a.y + p.y;
            X[4*j+2] = a.z + p.z;
            X[4*j+3] = a.w + p.w;
        }
    }

    // ---------------- QKV: outer-product over d, 48 acc chains ----------------
    float q[DIM], k[DIM], v[DIM];
    #pragma unroll
    for (int e = 0; e < DIM; ++e) { q[e] = bq[e]; k[e] = bk[e]; v[e] = bv[e]; }
    #pragma unroll
    for (int d = 0; d < DIM; ++d) {
        const float xd = X[d];
        #pragma unroll
        for (int e = 0; e < DIM; ++e) {
            q[e] += xd * Wq[d * DIM + e];
            k[e] += xd * Wk[d * DIM + e];
            v[e] += xd * Wv[d * DIM + e];
        }
    }

    // ---------------- attention scores via XOR butterfly ----------------
    float sc[SEQ];
    {
        float s = 0.f;
        #pragma unroll
        for (int d = 0; d < DIM; ++d) s += q[d] * k[d];      // t = 0 (self)
        sc[0] = s * 0.25f;
    }
    #define SCORE_PHASE(T, IMM)                                   \
    {                                                             \
        float s = 0.f;                                            \
        _Pragma("unroll")                                         \
        for (int d = 0; d < DIM; ++d) s += q[d] * SWZF(k[d], IMM);\
        sc[T] = s * 0.25f;                                        \
    }
    SCORE_PHASE(1, 0x041F)
    SCORE_PHASE(2, 0x081F)
    SCORE_PHASE(3, 0x0C1F)
    SCORE_PHASE(4, 0x101F)
    SCORE_PHASE(5, 0x141F)
    SCORE_PHASE(6, 0x181F)
    SCORE_PHASE(7, 0x1C1F)
    #undef SCORE_PHASE

    // ---------------- softmax over the 8 scores (per-lane) ----------------
    float mx = sc[0];
    #pragma unroll
    for (int m = 1; m < SEQ; ++m) mx = fmaxf(mx, sc[m]);
    float sum = 0.f;
    float w[SEQ];
    #pragma unroll
    for (int m = 0; m < SEQ; ++m) { w[m] = __expf(sc[m] - mx); sum += w[m]; }
    const float inv = 1.0f / sum;
    #pragma unroll
    for (int m = 0; m < SEQ; ++m) w[m] *= inv;

    // ---------------- PV via XOR butterfly ----------------
    float at[DIM];
    #pragma unroll
    for (int d = 0; d < DIM; ++d) at[d] = w[0] * v[d];       // t = 0 (self)
    #define PV_PHASE(T, IMM)                                      \
    {                                                             \
        const float wt = w[T];                                    \
        _Pragma("unroll")                                         \
        for (int d = 0; d < DIM; ++d) at[d] += wt * SWZF(v[d], IMM);\
    }
    PV_PHASE(1, 0x041F)
    PV_PHASE(2, 0x081F)
    PV_PHASE(3, 0x0C1F)
    PV_PHASE(4, 0x101F)
    PV_PHASE(5, 0x141F)
    PV_PHASE(6, 0x181F)
    PV_PHASE(7, 0x1C1F)
    #undef PV_PHASE

    // ---------------- O projection + residual ----------------
    float X1[DIM];
    #pragma unroll
    for (int e = 0; e < DIM; ++e) X1[e] = X[e] + bo[e];
    #pragma unroll
    for (int d = 0; d < DIM; ++d) {
        const float ad = at[d];
        #pragma unroll
        for (int e = 0; e < DIM; ++e) X1[e] += ad * Wo[d * DIM + e];
    }

    // ---------------- FFN + residual ----------------
    float h[FF];
    #pragma unroll
    for (int f = 0; f < FF; ++f) h[f] = b1[f];
    #pragma unroll
    for (int d = 0; d < DIM; ++d) {
        const float xd = X1[d];
        #pragma unroll
        for (int f = 0; f < FF; ++f) h[f] += xd * W1[d * FF + f];
    }
    #pragma unroll
    for (int f = 0; f < FF; ++f) h[f] = fmaxf(h[f], 0.f);

    float X2[DIM];
    #pragma unroll
    for (int e = 0; e < DIM; ++e) X2[e] = X1[e] + b2[e];
    #pragma unroll
    for (int f = 0; f < FF; ++f) {
        const float hf = h[f];
        #pragma unroll
        for (int e = 0; e < DIM; ++e) X2[e] += hf * W2[f * DIM + e];
    }

    // ---------------- write X2 row ----------------
    float4* dst = (float4*)(xout + row * DIM);
    #pragma unroll
    for (int j = 0; j < 4; ++j) {
        float4 xx;
        xx.x = X2[4*j+0]; xx.y = X2[4*j+1]; xx.z = X2[4*j+2]; xx.w = X2[4*j+3];
        dst[j] = xx;
    }
}

// ---------------------------------------------------------------------------
// Kernel B: vocab head GEMM [R,16] @ [16,256] + bias. (write-BW-bound, ~49us)
// ---------------------------------------------------------------------------
#define ROWS_PER_BLOCK 32

__global__ __launch_bounds__(256) void head_kernel(
    const float* __restrict__ xin,
    const float* __restrict__ Wh,
    const float* __restrict__ bh,
    float* __restrict__ out)
{
    const int tid = threadIdx.x;
    const int col = tid;
    float wh[DIM];
    #pragma unroll
    for (int d = 0; d < DIM; ++d) wh[d] = Wh[d * VOCAB + col];
    const float bhv = bh[col];

    const size_t row0 = (size_t)blockIdx.x * ROWS_PER_BLOCK;
    #pragma unroll 4
    for (int r = 0; r < ROWS_PER_BLOCK; ++r) {
        const float* xr = xin + (row0 + r) * DIM;  // wave-uniform address
        float acc = bhv;
        #pragma unroll
        for (int d = 0; d < DIM; ++d) acc += xr[d] * wh[d];
        out[(row0 + r) * VOCAB + col] = acc;
    }
}

// ---------------------------------------------------------------------------
// Fallback (ws too small): round-1 fused kernel.
// ---------------------------------------------------------------------------
#define ITEMS_PER_BLOCK 32
#define ITEM_STRIDE 136

__global__ __launch_bounds__(256) void fused_fallback_kernel(
    const int* __restrict__ x,
    const float* __restrict__ token_embed,
    const float* __restrict__ pos_embed,
    const float* __restrict__ Wq, const float* __restrict__ bq,
    const float* __restrict__ Wk, const float* __restrict__ bk,
    const float* __restrict__ Wv, const float* __restrict__ bv,
    const float* __restrict__ Wo, const float* __restrict__ bo,
    const float* __restrict__ W1, const float* __restrict__ b1,
    const float* __restrict__ W2, const float* __restrict__ b2,
    const float* __restrict__ Wh, const float* __restrict__ bh,
    float* __restrict__ out)
{
    __shared__ float sK[ITEMS_PER_BLOCK * ITEM_STRIDE];
    __shared__ float sV[ITEMS_PER_BLOCK * ITEM_STRIDE];

    const int tid = threadIdx.x;
    const int i = tid >> 3;
    const int n = tid & 7;
    const int b = blockIdx.x * ITEMS_PER_BLOCK + i;

    float X[DIM];
    {
        const int idx = x[b * SEQ + n];
        const float4* te = (const float4*)(token_embed + idx * DIM);
        const float4* pe = (const float4*)(pos_embed + n * DIM);
        #pragma unroll
        for (int j = 0; j < 4; ++j) {
            float4 a = te[j];
            float4 p = pe[j];
            X[4*j+0] = a.x + p.x; X[4*j+1] = a.y + p.y;
            X[4*j+2] = a.z + p.z; X[4*j+3] = a.w + p.w;
        }
    }

    float Q[DIM], Kr[DIM], Vr[DIM];
    #pragma unroll
    for (int e = 0; e < DIM; ++e) {
        float qq = bq[e], kk = bk[e], vv = bv[e];
        #pragma unroll
        for (int d = 0; d < DIM; ++d) {
            qq += X[d] * Wq[d * DIM + e];
            kk += X[d] * Wk[d * DIM + e];
            vv += X[d] * Wv[d * DIM + e];
        }
        Q[e] = qq; Kr[e] = kk; Vr[e] = vv;
    }
    {
        float* kdst = sK + i * ITEM_STRIDE + n * DIM;
        float* vdst = sV + i * ITEM_STRIDE + n * DIM;
        #pragma unroll
        for (int j = 0; j < 4; ++j) {
            float4 kk, vv;
            kk.x = Kr[4*j+0]; kk.y = Kr[4*j+1]; kk.z = Kr[4*j+2]; kk.w = Kr[4*j+3];
            vv.x = Vr[4*j+0]; vv.y = Vr[4*j+1]; vv.z = Vr[4*j+2]; vv.w = Vr[4*j+3];
            ((float4*)kdst)[j] = kk;
            ((float4*)vdst)[j] = vv;
        }
    }
    __syncthreads();

    float sc[SEQ];
    #pragma unroll
    for (int m = 0; m < SEQ; ++m) {
        const float* kr = sK + i * ITEM_STRIDE + m * DIM;
        float s = 0.f;
        #pragma unroll
        for (int d = 0; d < DIM; ++d) s += Q[d] * kr[d];
        sc[m] = s * 0.25f;
    }
    float mx = sc[0];
    #pragma unroll
    for (int m = 1; m < SEQ; ++m) mx = fmaxf(mx, sc[m]);
    float sum = 0.f;
    #pragma unroll
    for (int m = 0; m < SEQ; ++m) { sc[m] = __expf(sc[m] - mx); sum += sc[m]; }
    const float inv = 1.0f / sum;

    float at[DIM];
    #pragma unroll
    for (int d = 0; d < DIM; ++d) at[d] = 0.f;
    #pragma unroll
    for (int m = 0; m < SEQ; ++m) {
        const float w = sc[m] * inv;
        const float* vr = sV + i * ITEM_STRIDE + m * DIM;
        #pragma unroll
        for (int d = 0; d < DIM; ++d) at[d] += w * vr[d];
    }

    float X1[DIM];
    #pragma unroll
    for (int e = 0; e < DIM; ++e) {
        float o = bo[e];
        #pragma unroll
        for (int d = 0; d < DIM; ++d) o += at[d] * Wo[d * DIM + e];
        X1[e] = X[e] + o;
    }
    float h[FF];
    #pragma unroll
    for (int f = 0; f < FF; ++f) {
        float a = b1[f];
        #pragma unroll
        for (int d = 0; d < DIM; ++d) a += X1[d] * W1[d * FF + f];
        h[f] = fmaxf(a, 0.f);
    }
    float X2[DIM];
    #pragma unroll
    for (int e = 0; e < DIM; ++e) {
        float a = b2[e];
        #pragma unroll
        for (int f = 0; f < FF; ++f) a += h[f] * W2[f * DIM + e];
        X2[e] = X1[e] + a;
    }

    __syncthreads();
    {
        float* xdst = sK + i * ITEM_STRIDE + n * DIM;
        #pragma unroll
        for (int j = 0; j < 4; ++j) {
            float4 xx;
            xx.x = X2[4*j+0]; xx.y = X2[4*j+1]; xx.z = X2[4*j+2]; xx.w = X2[4*j+3];
            ((float4*)xdst)[j] = xx;
        }
    }
    __syncthreads();

    float wh[DIM];
    #pragma unroll
    for (int d = 0; d < DIM; ++d) wh[d] = Wh[d * VOCAB + tid];
    const float bhv = bh[tid];

    const size_t obase = (size_t)blockIdx.x * (ITEMS_PER_BLOCK * SEQ) * VOCAB + tid;
    #pragma unroll 4
    for (int r = 0; r < ITEMS_PER_BLOCK * SEQ; ++r) {
        const float* xr = sK + (r >> 3) * ITEM_STRIDE + (r & 7) * DIM;
        float acc = bhv;
        #pragma unroll
        for (int d = 0; d < DIM; ++d) acc += xr[d] * wh[d];
        out[obase + (size_t)r * VOCAB] = acc;
    }
}

extern "C" void kernel_launch(void* const* d_in, const int* in_sizes, int n_in,
                              void* d_out, int out_size, void* d_ws, size_t ws_size,
                              hipStream_t stream) {
    const int*   x           = (const int*)  d_in[0];
    const float* token_embed = (const float*)d_in[1];
    const float* pos_embed   = (const float*)d_in[2];
    const float* Wq = (const float*)d_in[3];
    const float* bq = (const float*)d_in[4];
    const float* Wk = (const float*)d_in[5];
    const float* bk = (const float*)d_in[6];
    const float* Wv = (const float*)d_in[7];
    const float* bv = (const float*)d_in[8];
    const float* Wo = (const float*)d_in[9];
    const float* bo = (const float*)d_in[10];
    const float* W1 = (const float*)d_in[11];
    const float* b1 = (const float*)d_in[12];
    const float* W2 = (const float*)d_in[13];
    const float* b2 = (const float*)d_in[14];
    const float* Wh = (const float*)d_in[15];
    const float* bh = (const float*)d_in[16];
    float* out = (float*)d_out;

    const int B = in_sizes[0] / SEQ;                 // 32768
    const int nrows = B * SEQ;                       // 262144
    const size_t ws_needed = (size_t)nrows * DIM * sizeof(float);  // 16 MB

    if (ws_size >= ws_needed) {
        float* xws = (float*)d_ws;
        body_kernel<<<nrows / 256, 256, 0, stream>>>(
            x, token_embed, pos_embed, Wq, bq, Wk, bk, Wv, bv, Wo, bo,
            W1, b1, W2, b2, xws);
        head_kernel<<<nrows / ROWS_PER_BLOCK, 256, 0, stream>>>(
            xws, Wh, bh, out);
    } else {
        fused_fallback_kernel<<<B / ITEMS_PER_BLOCK, 256, 0, stream>>>(
            x, token_embed, pos_embed, Wq, bq, Wk, bk, Wv, bv, Wo, bo,
            W1, b1, W2, b2, Wh, bh, out);
    }
}